// Round 13
// baseline (266.838 us; speedup 1.0000x reference)
//
#include <hip/hip_runtime.h>

typedef __attribute__((ext_vector_type(4))) float f32x4;
typedef __attribute__((ext_vector_type(8))) _Float16 f16x8;

#define D 256          // D_in == D_out == 256
#define VBS 128        // ghost batch rows per chunk
#define BN_EPS 1e-5f

// ---------------------------------------------------------------- pack W
// Pack W[k][n] (f32, row-major 256x256) into f16 MFMA fragment order.
// frag value = W[kb*32+(l>>4)*8+j][ct*16+(l&15)], frag (kb,ct,lane) at
// wp + ((kb*16+ct)*64+lane)*8.
__global__ void pack_w_kernel(const float* __restrict__ W, _Float16* __restrict__ wp) {
    int idx = blockIdx.x * blockDim.x + threadIdx.x;   // [0, 8192)
    int kb  = idx >> 10;
    int rem = idx & 1023;
    int ct  = rem >> 6;
    int l   = rem & 63;
    int col = ct * 16 + (l & 15);
    int k0  = kb * 32 + ((l >> 4) << 3);
    f16x8 v;
#pragma unroll
    for (int j = 0; j < 8; ++j) v[j] = (_Float16)W[(k0 + j) * D + col];
    *reinterpret_cast<f16x8*>(wp + (size_t)idx * 8) = v;
}

// 16-lane (DPP row) all-lanes sum: VALU pipe only.
template <int CTRL>
__device__ __forceinline__ float row_ror_add(float x) {
    int v = __builtin_amdgcn_update_dpp(0, __builtin_bit_cast(int, x),
                                        CTRL, 0xF, 0xF, true);
    return x + __builtin_bit_cast(float, v);
}
__device__ __forceinline__ float rsum16(float x) {
    x = row_ror_add<0x128>(x);
    x = row_ror_add<0x124>(x);
    x = row_ror_add<0x122>(x);
    x = row_ror_add<0x121>(x);
    return x;
}

#define GLL16(g, l)                                                     \
    __builtin_amdgcn_global_load_lds(                                   \
        (const __attribute__((address_space(1))) unsigned*)(g),         \
        (__attribute__((address_space(3))) unsigned*)(l), 16, 0, 0)

// LDS map (bytes):
//   [0,131072)        full packed W, resident for the whole kernel
//   [131072,139264)   sSum[8][256]     [139264,147456) sSq[8][256]
//   [147456,148480)   sA               [148480,149504) sB
//
// PERSISTENT blocks (grid=256): W staged into LDS ONCE, then per chunk:
//   - a for the whole chunk in 16 register dwordx4 loads (16-deep MLP)
//   - K-loop: fully unrolled, BARRIER-FREE (W read-only, a in regs)
//   - 2 barriers/chunk total (BN stats). Next chunk's a prefetches
//     during the tau phase (after the barriers -> never drained).
// TRANSPOSED mfma: acc[ct] = mfma(W-frag, a-frag); lane holds row
// (chunk*128 + wid*16 + (lane&15)), cols ct*16 + (lane>>4)*4 + {0..3}.
__global__ __launch_bounds__(512, 2)
void fused_kernel(const float* __restrict__ A, const float* __restrict__ priors,
                  const _Float16* __restrict__ Wp, const float* __restrict__ gamma,
                  const float* __restrict__ beta, float* __restrict__ out, int iters) {
    const int tid  = threadIdx.x;
    const int wid  = tid >> 6;    // 0..7
    const int lane = tid & 63;
    const int lrow = lane & 15;
    const int q    = lane >> 4;

    __shared__ char smem[149504];

    // ---- prologue: stage the full 128 KB W into LDS once ----
    {
        const char* ws = (const char*)Wp + (size_t)tid * 16;
        char* wd = smem + (size_t)tid * 16;
#pragma unroll
        for (int j = 0; j < 16; ++j) GLL16(ws + j * 8192, wd + j * 8192);
    }
    __syncthreads();   // one-time drain; W is read-only from here on

    float* sSum = (float*)(smem + 131072);
    float* sSq  = (float*)(smem + 139264);
    float* sA   = (float*)(smem + 147456);
    float* sB   = (float*)(smem + 148480);

    const int c0 = blockIdx.x;
    const int GRID = gridDim.x;
    // a-frag for this thread: row = chunk*128 + wid*16 + lrow, k = kb*32+q*8+{0..7}
    const float* abase = A + (size_t)(c0 * VBS + wid * 16 + lrow) * D + q * 8;
    const size_t CSTR = (size_t)GRID * VBS * D;   // floats per chunk stride

    // first chunk's a: 16 dwordx4 loads in flight
    f32x4 aL[8], aH[8];
#pragma unroll
    for (int kb = 0; kb < 8; ++kb) {
        aL[kb] = *reinterpret_cast<const f32x4*>(abase + kb * 32);
        aH[kb] = *reinterpret_cast<const f32x4*>(abase + kb * 32 + 4);
    }

#pragma unroll 1
    for (int it = 0; it < iters; ++it) {
        const int myrow = (c0 + it * GRID) * VBS + wid * 16 + lrow;

        f32x4 acc[16];
#pragma unroll
        for (int ct = 0; ct < 16; ++ct) { f32x4 z = {0.f, 0.f, 0.f, 0.f}; acc[ct] = z; }

        // ---- K-loop: no barriers, no staging; compiler-scheduled waits ----
#pragma unroll
        for (int kb = 0; kb < 8; ++kb) {
            f16x8 t;
#pragma unroll
            for (int j = 0; j < 4; ++j) {
                t[j]     = (_Float16)aL[kb][j];
                t[j + 4] = (_Float16)aH[kb][j];
            }
            const char* wb = smem + kb * 16384 + lane * 16;
#pragma unroll
            for (int ct = 0; ct < 16; ++ct) {
                f16x8 w = *reinterpret_cast<const f16x8*>(wb + ct * 1024);
                acc[ct] = __builtin_amdgcn_mfma_f32_16x16x32_f16(w, t, acc[ct], 0, 0, 0);
            }
        }

        // ---- priors prefetch: latency hidden under the stats phase ----
        const float* pr = priors + (size_t)myrow * D;
        f32x4 p[16];
#pragma unroll
        for (int ct = 0; ct < 16; ++ct)
            p[ct] = *reinterpret_cast<const f32x4*>(pr + ct * 16 + q * 4);

        // ---- Ghost BN stats (DPP rsum16 per 16-row strip; LDS combine) ----
#pragma unroll
        for (int ct = 0; ct < 16; ++ct) {
            f32x4 s = acc[ct];
            f32x4 qv = s * s;
#pragma unroll
            for (int c = 0; c < 4; ++c) { s[c] = rsum16(s[c]); qv[c] = rsum16(qv[c]); }
            if (lrow == 0) {
                *reinterpret_cast<f32x4*>(&sSum[wid * D + ct * 16 + q * 4]) = s;
                *reinterpret_cast<f32x4*>(&sSq [wid * D + ct * 16 + q * 4]) = qv;
            }
        }
        __syncthreads();
        if (tid < D) {
            float s = 0.f, qq = 0.f;
#pragma unroll
            for (int w = 0; w < 8; ++w) { s += sSum[w * D + tid]; qq += sSq[w * D + tid]; }
            float mean = s * (1.0f / 128.0f);
            float var  = qq * (1.0f / 128.0f) - mean * mean;
            float g    = gamma[tid] * rsqrtf(var + BN_EPS);
            sA[tid] = g;
            sB[tid] = beta[tid] - mean * g;
        }
        __syncthreads();

        // ---- apply BN * priors; track row max AND row sum ----
        float m = -1e30f, ssum = 0.f;
#pragma unroll
        for (int ct = 0; ct < 16; ++ct) {
            int cc = ct * 16 + q * 4;
            f32x4 ga = *reinterpret_cast<const f32x4*>(&sA[cc]);
            f32x4 bb = *reinterpret_cast<const f32x4*>(&sB[cc]);
            f32x4 x  = (acc[ct] * ga + bb) * p[ct];
            acc[ct] = x;
            m = fmaxf(m, fmaxf(fmaxf(x[0], x[1]), fmaxf(x[2], x[3])));
            ssum += (x[0] + x[1]) + (x[2] + x[3]);
        }
        m = fmaxf(m, __shfl_xor(m, 16));
        m = fmaxf(m, __shfl_xor(m, 32));
        ssum += __shfl_xor(ssum, 16);
        ssum += __shfl_xor(ssum, 32);

        // ---- next chunk's a prefetch: flies under the tau loop/stores ----
        if (it + 1 < iters) {
            const float* an = abase + (size_t)(it + 1) * CSTR;
#pragma unroll
            for (int kb = 0; kb < 8; ++kb) {
                aL[kb] = *reinterpret_cast<const f32x4*>(an + kb * 32);
                aH[kb] = *reinterpret_cast<const f32x4*>(an + kb * 32 + 4);
            }
        }

        // Michelot fixed-point. Both seeds provably <= tau*:
        //   m-1 (max support) and (sum_all-1)/256 (full support step).
        float tau = fmaxf(m - 1.0f, (ssum - 1.0f) * (1.0f / 256.0f));
#pragma unroll 1
        for (int itr = 0; itr < 32; ++itr) {
            float s = 0.f, c = 0.f;
#pragma unroll
            for (int ct = 0; ct < 16; ++ct)
#pragma unroll
                for (int k = 0; k < 4; ++k) {
                    float zz = acc[ct][k];
                    if (zz > tau) { s += zz; c += 1.f; }
                }
            s += __shfl_xor(s, 16); c += __shfl_xor(c, 16);
            s += __shfl_xor(s, 32); c += __shfl_xor(c, 32);
            float n = (s - 1.0f) / c;
            bool done = (n <= tau);
            tau = fmaxf(tau, n);
            if (__all(done)) break;
        }

        float* ob = out + (size_t)myrow * D;
#pragma unroll
        for (int ct = 0; ct < 16; ++ct) {
            int cc = ct * 16 + q * 4;
            f32x4 x = acc[ct];
            f32x4 r;
#pragma unroll
            for (int k = 0; k < 4; ++k) r[k] = fmaxf(x[k] - tau, 0.f);
            *reinterpret_cast<f32x4*>(&ob[cc]) = r;
        }
    }
}

extern "C" void kernel_launch(void* const* d_in, const int* in_sizes, int n_in,
                              void* d_out, int out_size, void* d_ws, size_t ws_size,
                              hipStream_t stream) {
    const float* a      = (const float*)d_in[0];
    const float* priors = (const float*)d_in[1];
    const float* W      = (const float*)d_in[2];
    // d_in[3] = b : unused — ghost-BN mean subtraction cancels any per-column bias.
    const float* gamma  = (const float*)d_in[4];
    const float* beta   = (const float*)d_in[5];
    float* out = (float*)d_out;
    _Float16* wp = (_Float16*)d_ws;   // 256*256 f16 = 128 KB packed W

    const int B = in_sizes[0] / D;        // 262144
    const int nchunks = B / VBS;          // 2048

    hipLaunchKernelGGL(pack_w_kernel, dim3(32), dim3(256), 0, stream, W, wp);

    int grid = 256, iters = nchunks / 256;
    if (nchunks % 256 != 0) { grid = nchunks; iters = 1; }   // robustness fallback
    hipLaunchKernelGGL(fused_kernel, dim3(grid), dim3(512), 0, stream,
                       a, priors, wp, gamma, beta, out, iters);
}

// Round 14
// 266.239 us; speedup vs baseline: 1.0023x; 1.0023x over previous
//
#include <hip/hip_runtime.h>

typedef __attribute__((ext_vector_type(4))) float f32x4;
typedef __attribute__((ext_vector_type(8))) _Float16 f16x8;

#define D 256          // D_in == D_out == 256
#define VBS 128        // ghost batch rows per chunk
#define BN_EPS 1e-5f

// ---------------------------------------------------------------- pack W
// Pack W[k][n] (f32, row-major 256x256) into f16 MFMA fragment order.
// frag value = W[kb*32+(l>>4)*8+j][ct*16+(l&15)], frag (kb,ct,lane) at
// wp + ((kb*16+ct)*64+lane)*8.
__global__ void pack_w_kernel(const float* __restrict__ W, _Float16* __restrict__ wp) {
    int idx = blockIdx.x * blockDim.x + threadIdx.x;   // [0, 8192)
    int kb  = idx >> 10;
    int rem = idx & 1023;
    int ct  = rem >> 6;
    int l   = rem & 63;
    int col = ct * 16 + (l & 15);
    int k0  = kb * 32 + ((l >> 4) << 3);
    f16x8 v;
#pragma unroll
    for (int j = 0; j < 8; ++j) v[j] = (_Float16)W[(k0 + j) * D + col];
    *reinterpret_cast<f16x8*>(wp + (size_t)idx * 8) = v;
}

// 16-lane (DPP row) all-lanes sum: VALU pipe only.
template <int CTRL>
__device__ __forceinline__ float row_ror_add(float x) {
    int v = __builtin_amdgcn_update_dpp(0, __builtin_bit_cast(int, x),
                                        CTRL, 0xF, 0xF, true);
    return x + __builtin_bit_cast(float, v);
}
__device__ __forceinline__ float rsum16(float x) {
    x = row_ror_add<0x128>(x);
    x = row_ror_add<0x124>(x);
    x = row_ror_add<0x122>(x);
    x = row_ror_add<0x121>(x);
    return x;
}

#define GLL16(g, l)                                                     \
    __builtin_amdgcn_global_load_lds(                                   \
        (const __attribute__((address_space(1))) unsigned*)(g),         \
        (__attribute__((address_space(3))) unsigned*)(l), 16, 0, 0)

// LDS map (bytes):
//   [0,131072)        full packed W, resident for the whole kernel
//   [131072,139264)   sSum[8][256]     [139264,147456) sSq[8][256]
//   [147456,148480)   sA               [148480,149504) sB
//
// PERSISTENT blocks (grid=256): W staged into LDS ONCE, then per chunk:
//   - a for the whole chunk in 16 register dwordx4 loads (16-deep MLP),
//     issued during the PREVIOUS chunk's tau phase
//   - K-loop: fully unrolled, BARRIER-FREE (W read-only, a in regs)
//   - 2 barriers/chunk total (BN stats).
// __launch_bounds__(512,1): LDS already limits to 1 block/CU, so take the
// full 512-VGPR budget -> acc(64)+a(64)+p(64)+temps fits with NO spill.
// (R13's (512,2) imposed a 128-reg cap -> spill -> +113 MB scratch traffic.)
__global__ __launch_bounds__(512, 1)
void fused_kernel(const float* __restrict__ A, const float* __restrict__ priors,
                  const _Float16* __restrict__ Wp, const float* __restrict__ gamma,
                  const float* __restrict__ beta, float* __restrict__ out, int iters) {
    const int tid  = threadIdx.x;
    const int wid  = tid >> 6;    // 0..7
    const int lane = tid & 63;
    const int lrow = lane & 15;
    const int q    = lane >> 4;

    __shared__ char smem[149504];

    // ---- prologue: stage the full 128 KB W into LDS once ----
    {
        const char* ws = (const char*)Wp + (size_t)tid * 16;
        char* wd = smem + (size_t)tid * 16;
#pragma unroll
        for (int j = 0; j < 16; ++j) GLL16(ws + j * 8192, wd + j * 8192);
    }
    __syncthreads();   // one-time drain; W is read-only from here on

    float* sSum = (float*)(smem + 131072);
    float* sSq  = (float*)(smem + 139264);
    float* sA   = (float*)(smem + 147456);
    float* sB   = (float*)(smem + 148480);

    const int c0 = blockIdx.x;
    const int GRID = gridDim.x;
    // a-frag for this thread: row = chunk*128 + wid*16 + lrow, k = kb*32+q*8+{0..7}
    const float* abase = A + (size_t)(c0 * VBS + wid * 16 + lrow) * D + q * 8;
    const size_t CSTR = (size_t)GRID * VBS * D;   // floats per chunk stride

    // first chunk's a: 16 dwordx4 loads in flight
    f32x4 aL[8], aH[8];
#pragma unroll
    for (int kb = 0; kb < 8; ++kb) {
        aL[kb] = *reinterpret_cast<const f32x4*>(abase + kb * 32);
        aH[kb] = *reinterpret_cast<const f32x4*>(abase + kb * 32 + 4);
    }

#pragma unroll 1
    for (int it = 0; it < iters; ++it) {
        const int myrow = (c0 + it * GRID) * VBS + wid * 16 + lrow;

        f32x4 acc[16];
#pragma unroll
        for (int ct = 0; ct < 16; ++ct) { f32x4 z = {0.f, 0.f, 0.f, 0.f}; acc[ct] = z; }

        // ---- K-loop: no barriers, no staging; compiler-scheduled waits ----
#pragma unroll
        for (int kb = 0; kb < 8; ++kb) {
            f16x8 t;
#pragma unroll
            for (int j = 0; j < 4; ++j) {
                t[j]     = (_Float16)aL[kb][j];
                t[j + 4] = (_Float16)aH[kb][j];
            }
            const char* wb = smem + kb * 16384 + lane * 16;
#pragma unroll
            for (int ct = 0; ct < 16; ++ct) {
                f16x8 w = *reinterpret_cast<const f16x8*>(wb + ct * 1024);
                acc[ct] = __builtin_amdgcn_mfma_f32_16x16x32_f16(w, t, acc[ct], 0, 0, 0);
            }
        }

        // ---- priors prefetch: latency hidden under the stats phase ----
        const float* pr = priors + (size_t)myrow * D;
        f32x4 p[16];
#pragma unroll
        for (int ct = 0; ct < 16; ++ct)
            p[ct] = *reinterpret_cast<const f32x4*>(pr + ct * 16 + q * 4);

        // ---- Ghost BN stats (DPP rsum16 per 16-row strip; LDS combine) ----
#pragma unroll
        for (int ct = 0; ct < 16; ++ct) {
            f32x4 s = acc[ct];
            f32x4 qv = s * s;
#pragma unroll
            for (int c = 0; c < 4; ++c) { s[c] = rsum16(s[c]); qv[c] = rsum16(qv[c]); }
            if (lrow == 0) {
                *reinterpret_cast<f32x4*>(&sSum[wid * D + ct * 16 + q * 4]) = s;
                *reinterpret_cast<f32x4*>(&sSq [wid * D + ct * 16 + q * 4]) = qv;
            }
        }
        __syncthreads();
        if (tid < D) {
            float s = 0.f, qq = 0.f;
#pragma unroll
            for (int w = 0; w < 8; ++w) { s += sSum[w * D + tid]; qq += sSq[w * D + tid]; }
            float mean = s * (1.0f / 128.0f);
            float var  = qq * (1.0f / 128.0f) - mean * mean;
            float g    = gamma[tid] * rsqrtf(var + BN_EPS);
            sA[tid] = g;
            sB[tid] = beta[tid] - mean * g;
        }
        __syncthreads();

        // ---- apply BN * priors; track row max AND row sum ----
        float m = -1e30f, ssum = 0.f;
#pragma unroll
        for (int ct = 0; ct < 16; ++ct) {
            int cc = ct * 16 + q * 4;
            f32x4 ga = *reinterpret_cast<const f32x4*>(&sA[cc]);
            f32x4 bb = *reinterpret_cast<const f32x4*>(&sB[cc]);
            f32x4 x  = (acc[ct] * ga + bb) * p[ct];
            acc[ct] = x;
            m = fmaxf(m, fmaxf(fmaxf(x[0], x[1]), fmaxf(x[2], x[3])));
            ssum += (x[0] + x[1]) + (x[2] + x[3]);
        }
        m = fmaxf(m, __shfl_xor(m, 16));
        m = fmaxf(m, __shfl_xor(m, 32));
        ssum += __shfl_xor(ssum, 16);
        ssum += __shfl_xor(ssum, 32);

        // ---- next chunk's a prefetch: flies under the tau loop/stores ----
        if (it + 1 < iters) {
            const float* an = abase + (size_t)(it + 1) * CSTR;
#pragma unroll
            for (int kb = 0; kb < 8; ++kb) {
                aL[kb] = *reinterpret_cast<const f32x4*>(an + kb * 32);
                aH[kb] = *reinterpret_cast<const f32x4*>(an + kb * 32 + 4);
            }
        }

        // Michelot fixed-point. Both seeds provably <= tau*:
        //   m-1 (max support) and (sum_all-1)/256 (full support step).
        float tau = fmaxf(m - 1.0f, (ssum - 1.0f) * (1.0f / 256.0f));
#pragma unroll 1
        for (int itr = 0; itr < 32; ++itr) {
            float s = 0.f, c = 0.f;
#pragma unroll
            for (int ct = 0; ct < 16; ++ct)
#pragma unroll
                for (int k = 0; k < 4; ++k) {
                    float zz = acc[ct][k];
                    if (zz > tau) { s += zz; c += 1.f; }
                }
            s += __shfl_xor(s, 16); c += __shfl_xor(c, 16);
            s += __shfl_xor(s, 32); c += __shfl_xor(c, 32);
            float n = (s - 1.0f) / c;
            bool done = (n <= tau);
            tau = fmaxf(tau, n);
            if (__all(done)) break;
        }

        float* ob = out + (size_t)myrow * D;
#pragma unroll
        for (int ct = 0; ct < 16; ++ct) {
            int cc = ct * 16 + q * 4;
            f32x4 x = acc[ct];
            f32x4 r;
#pragma unroll
            for (int k = 0; k < 4; ++k) r[k] = fmaxf(x[k] - tau, 0.f);
            *reinterpret_cast<f32x4*>(&ob[cc]) = r;
        }
    }
}

extern "C" void kernel_launch(void* const* d_in, const int* in_sizes, int n_in,
                              void* d_out, int out_size, void* d_ws, size_t ws_size,
                              hipStream_t stream) {
    const float* a      = (const float*)d_in[0];
    const float* priors = (const float*)d_in[1];
    const float* W      = (const float*)d_in[2];
    // d_in[3] = b : unused — ghost-BN mean subtraction cancels any per-column bias.
    const float* gamma  = (const float*)d_in[4];
    const float* beta   = (const float*)d_in[5];
    float* out = (float*)d_out;
    _Float16* wp = (_Float16*)d_ws;   // 256*256 f16 = 128 KB packed W

    const int B = in_sizes[0] / D;        // 262144
    const int nchunks = B / VBS;          // 2048

    hipLaunchKernelGGL(pack_w_kernel, dim3(32), dim3(256), 0, stream, W, wp);

    int grid = 256, iters = nchunks / 256;
    if (nchunks % 256 != 0) { grid = nchunks; iters = 1; }   // robustness fallback
    hipLaunchKernelGGL(fused_kernel, dim3(grid), dim3(512), 0, stream,
                       a, priors, wp, gamma, beta, out, iters);
}

// Round 15
// 209.676 us; speedup vs baseline: 1.2726x; 1.2698x over previous
//
#include <hip/hip_runtime.h>

typedef __attribute__((ext_vector_type(4))) float f32x4;
typedef __attribute__((ext_vector_type(8))) _Float16 f16x8;

#define D 256          // D_in == D_out == 256
#define VBS 128        // ghost batch rows per chunk
#define BN_EPS 1e-5f

// ---------------------------------------------------------------- pack W
// Pack W[k][n] (f32, row-major 256x256) into f16 MFMA fragment order.
// frag value = W[kb*32+(l>>4)*8+j][ct*16+(l&15)], frag (kb,ct,lane) at
// wp + ((kb*16+ct)*64+lane)*8.
__global__ void pack_w_kernel(const float* __restrict__ W, _Float16* __restrict__ wp) {
    int idx = blockIdx.x * blockDim.x + threadIdx.x;   // [0, 8192)
    int kb  = idx >> 10;
    int rem = idx & 1023;
    int ct  = rem >> 6;
    int l   = rem & 63;
    int col = ct * 16 + (l & 15);
    int k0  = kb * 32 + ((l >> 4) << 3);
    f16x8 v;
#pragma unroll
    for (int j = 0; j < 8; ++j) v[j] = (_Float16)W[(k0 + j) * D + col];
    *reinterpret_cast<f16x8*>(wp + (size_t)idx * 8) = v;
}

// 16-lane (DPP row) all-lanes sum: VALU pipe only.
template <int CTRL>
__device__ __forceinline__ float row_ror_add(float x) {
    int v = __builtin_amdgcn_update_dpp(0, __builtin_bit_cast(int, x),
                                        CTRL, 0xF, 0xF, true);
    return x + __builtin_bit_cast(float, v);
}
__device__ __forceinline__ float rsum16(float x) {
    x = row_ror_add<0x128>(x);
    x = row_ror_add<0x124>(x);
    x = row_ror_add<0x122>(x);
    x = row_ror_add<0x121>(x);
    return x;
}

#define GLL16(g, l)                                                     \
    __builtin_amdgcn_global_load_lds(                                   \
        (const __attribute__((address_space(1))) unsigned*)(g),         \
        (__attribute__((address_space(3))) unsigned*)(l), 16, 0, 0)

// LDS map (bytes):
//   [0,131072)        full packed W, resident for the whole kernel
//   [131072,139264)   sSum[8][256]     [139264,147456) sSq[8][256]
//   [147456,148480)   sA               [148480,149504) sB
//
// PERSISTENT blocks (grid=256): W staged into LDS ONCE; per chunk:
//   - a loaded per-K-step into a 2-deep rotating 16-reg window
//     (R13/R14 held the whole chunk = 64 regs -> spill; this doesn't)
//   - K-loop: fully unrolled, BARRIER-FREE (W read-only, a in regs)
//   - 2 raw s_barriers/chunk (stats), lgkmcnt-only (no vmcnt drain:
//     priors prefetch and next-chunk a stay in flight across them)
// TRANSPOSED mfma: acc[ct] = mfma(W-frag, a-frag); lane holds row
// (chunk*128 + wid*16 + (lane&15)), cols ct*16 + (lane>>4)*4 + {0..3}.
__global__ __launch_bounds__(512)
void fused_kernel(const float* __restrict__ A, const float* __restrict__ priors,
                  const _Float16* __restrict__ Wp, const float* __restrict__ gamma,
                  const float* __restrict__ beta, float* __restrict__ out, int iters) {
    const int tid  = threadIdx.x;
    const int wid  = tid >> 6;    // 0..7
    const int lane = tid & 63;
    const int lrow = lane & 15;
    const int q    = lane >> 4;

    __shared__ char smem[149504];

    // ---- prologue: stage the full 128 KB W into LDS once ----
    {
        const char* ws = (const char*)Wp + (size_t)tid * 16;
        char* wd = smem + (size_t)tid * 16;
#pragma unroll
        for (int j = 0; j < 16; ++j) GLL16(ws + j * 8192, wd + j * 8192);
    }
    __syncthreads();   // one-time drain; W is read-only from here on

    float* sSum = (float*)(smem + 131072);
    float* sSq  = (float*)(smem + 139264);
    float* sA   = (float*)(smem + 147456);
    float* sB   = (float*)(smem + 148480);

    const int c0 = blockIdx.x;
    const int GRID = gridDim.x;
    // a-frag for this thread: row = chunk*128 + wid*16 + lrow, k = kb*32+q*8+{0..7}
    const float* abase = A + (size_t)(c0 * VBS + wid * 16 + lrow) * D + q * 8;
    const size_t CSTR = (size_t)GRID * VBS * D;   // floats per chunk stride

    // 2-deep rotating a window (named slots -> static indexing, no scratch)
    f32x4 aL0, aH0, aL1, aH1;
    aL0 = *reinterpret_cast<const f32x4*>(abase);
    aH0 = *reinterpret_cast<const f32x4*>(abase + 4);
    aL1 = *reinterpret_cast<const f32x4*>(abase + 32);
    aH1 = *reinterpret_cast<const f32x4*>(abase + 36);

#pragma unroll 1
    for (int it = 0; it < iters; ++it) {
        const int myrow = (c0 + it * GRID) * VBS + wid * 16 + lrow;
        const float* ac = abase + (size_t)it * CSTR;

        f32x4 acc[16];
#pragma unroll
        for (int ct = 0; ct < 16; ++ct) { f32x4 z = {0.f, 0.f, 0.f, 0.f}; acc[ct] = z; }

        // ---- K-loop: barrier-free; a window rotates 2 steps ahead ----
#pragma unroll
        for (int kb = 0; kb < 8; ++kb) {
            f32x4 al = (kb & 1) ? aL1 : aL0;
            f32x4 ah = (kb & 1) ? aH1 : aH0;
            f16x8 t;
#pragma unroll
            for (int j = 0; j < 4; ++j) { t[j] = (_Float16)al[j]; t[j + 4] = (_Float16)ah[j]; }
            if (kb < 6) {   // refill the slot just consumed with step kb+2
                const float* an = ac + (kb + 2) * 32;
                if (kb & 1) { aL1 = *reinterpret_cast<const f32x4*>(an);
                              aH1 = *reinterpret_cast<const f32x4*>(an + 4); }
                else        { aL0 = *reinterpret_cast<const f32x4*>(an);
                              aH0 = *reinterpret_cast<const f32x4*>(an + 4); }
            }
            const char* wb = smem + kb * 16384 + lane * 16;
#pragma unroll
            for (int ct = 0; ct < 16; ++ct) {
                f16x8 w = *reinterpret_cast<const f16x8*>(wb + ct * 1024);
                acc[ct] = __builtin_amdgcn_mfma_f32_16x16x32_f16(w, t, acc[ct], 0, 0, 0);
            }
        }

        // ---- priors prefetch: flies through the stats barriers ----
        const float* pr = priors + (size_t)myrow * D;
        f32x4 p[16];
#pragma unroll
        for (int ct = 0; ct < 16; ++ct)
            p[ct] = *reinterpret_cast<const f32x4*>(pr + ct * 16 + q * 4);

        // ---- next chunk's first a window: also issued before the barriers ----
        if (it + 1 < iters) {
            const float* an = ac + CSTR;
            aL0 = *reinterpret_cast<const f32x4*>(an);
            aH0 = *reinterpret_cast<const f32x4*>(an + 4);
            aL1 = *reinterpret_cast<const f32x4*>(an + 32);
            aH1 = *reinterpret_cast<const f32x4*>(an + 36);
        }

        // ---- Ghost BN stats (DPP rsum16 per 16-row strip; LDS combine) ----
#pragma unroll
        for (int ct = 0; ct < 16; ++ct) {
            f32x4 s = acc[ct];
            f32x4 qv = s * s;
#pragma unroll
            for (int c = 0; c < 4; ++c) { s[c] = rsum16(s[c]); qv[c] = rsum16(qv[c]); }
            if (lrow == 0) {
                *reinterpret_cast<f32x4*>(&sSum[wid * D + ct * 16 + q * 4]) = s;
                *reinterpret_cast<f32x4*>(&sSq [wid * D + ct * 16 + q * 4]) = qv;
            }
        }
        // raw barrier: protect LDS stats only; vmem (p, a) stays in flight
        asm volatile("s_waitcnt lgkmcnt(0)" ::: "memory");
        __builtin_amdgcn_s_barrier();
        asm volatile("" ::: "memory");
        if (tid < D) {
            float s = 0.f, qq = 0.f;
#pragma unroll
            for (int w = 0; w < 8; ++w) { s += sSum[w * D + tid]; qq += sSq[w * D + tid]; }
            float mean = s * (1.0f / 128.0f);
            float var  = qq * (1.0f / 128.0f) - mean * mean;
            float g    = gamma[tid] * rsqrtf(var + BN_EPS);
            sA[tid] = g;
            sB[tid] = beta[tid] - mean * g;
        }
        asm volatile("s_waitcnt lgkmcnt(0)" ::: "memory");
        __builtin_amdgcn_s_barrier();
        asm volatile("" ::: "memory");

        // ---- apply BN * priors; track row max AND row sum ----
        float m = -1e30f, ssum = 0.f;
#pragma unroll
        for (int ct = 0; ct < 16; ++ct) {
            int cc = ct * 16 + q * 4;
            f32x4 ga = *reinterpret_cast<const f32x4*>(&sA[cc]);
            f32x4 bb = *reinterpret_cast<const f32x4*>(&sB[cc]);
            f32x4 x  = (acc[ct] * ga + bb) * p[ct];
            acc[ct] = x;
            m = fmaxf(m, fmaxf(fmaxf(x[0], x[1]), fmaxf(x[2], x[3])));
            ssum += (x[0] + x[1]) + (x[2] + x[3]);
        }
        m = fmaxf(m, __shfl_xor(m, 16));
        m = fmaxf(m, __shfl_xor(m, 32));
        ssum += __shfl_xor(ssum, 16);
        ssum += __shfl_xor(ssum, 32);

        // Michelot fixed-point. Both seeds provably <= tau*:
        //   m-1 (max support) and (sum_all-1)/256 (full support step).
        float tau = fmaxf(m - 1.0f, (ssum - 1.0f) * (1.0f / 256.0f));
#pragma unroll 1
        for (int itr = 0; itr < 32; ++itr) {
            float s = 0.f, c = 0.f;
#pragma unroll
            for (int ct = 0; ct < 16; ++ct)
#pragma unroll
                for (int k = 0; k < 4; ++k) {
                    float zz = acc[ct][k];
                    if (zz > tau) { s += zz; c += 1.f; }
                }
            s += __shfl_xor(s, 16); c += __shfl_xor(c, 16);
            s += __shfl_xor(s, 32); c += __shfl_xor(c, 32);
            float n = (s - 1.0f) / c;
            bool done = (n <= tau);
            tau = fmaxf(tau, n);
            if (__all(done)) break;
        }

        float* ob = out + (size_t)myrow * D;
#pragma unroll
        for (int ct = 0; ct < 16; ++ct) {
            int cc = ct * 16 + q * 4;
            f32x4 x = acc[ct];
            f32x4 r;
#pragma unroll
            for (int k = 0; k < 4; ++k) r[k] = fmaxf(x[k] - tau, 0.f);
            *reinterpret_cast<f32x4*>(&ob[cc]) = r;
        }
    }
}

extern "C" void kernel_launch(void* const* d_in, const int* in_sizes, int n_in,
                              void* d_out, int out_size, void* d_ws, size_t ws_size,
                              hipStream_t stream) {
    const float* a      = (const float*)d_in[0];
    const float* priors = (const float*)d_in[1];
    const float* W      = (const float*)d_in[2];
    // d_in[3] = b : unused — ghost-BN mean subtraction cancels any per-column bias.
    const float* gamma  = (const float*)d_in[4];
    const float* beta   = (const float*)d_in[5];
    float* out = (float*)d_out;
    _Float16* wp = (_Float16*)d_ws;   // 256*256 f16 = 128 KB packed W

    const int B = in_sizes[0] / D;        // 262144
    const int nchunks = B / VBS;          // 2048

    hipLaunchKernelGGL(pack_w_kernel, dim3(32), dim3(256), 0, stream, W, wp);

    int grid = 256, iters = nchunks / 256;
    if (nchunks % 256 != 0) { grid = nchunks; iters = 1; }   // robustness fallback
    hipLaunchKernelGGL(fused_kernel, dim3(grid), dim3(512), 0, stream,
                       a, priors, wp, gamma, beta, out, iters);
}